// Round 4
// baseline (150.360 us; speedup 1.0000x reference)
//
#include <hip/hip_runtime.h>
#include <math.h>

#define BB 64
#define WW 128
#define FF 64
#define HH 4
#define OW 128

// XOR-swizzle on 16B granules for the fs/fd LDS tiles ([row][128] dwords,
// row stride 128 = 0 mod 32 banks). Column writes (fixed d, lanes = rows)
// and per-lane b128 reads land 4-way instead of 32-way conflicted; the
// wave-uniform broadcast reads are unaffected. Keeps d's low 2 bits so a
// 4-dword granule stays contiguous/aligned.
__device__ __forceinline__ int swz(int row, int d) {
    return (((d & ~3) ^ ((row & 31) << 2)) | (d & 3));
}

// ---------------------------------------------------------------------------
// Fused: projection (this head's slice) -> LDS, scores, edge-softmax,
// aggregation, per-head partial out. Grid 256 = (b,h), 1 block/CU.
// Block 1024 thr = 16 waves (4/SIMD). LDS ~105 KB.
// ---------------------------------------------------------------------------
__global__ __launch_bounds__(1024, 4) void gat_fused(
    const float* __restrict__ x,     // [B][W][F]
    const float* __restrict__ Wsrc,  // [512][128]
    const float* __restrict__ bsrc,
    const float* __restrict__ Wdst,
    const float* __restrict__ bdst,
    const float* __restrict__ attn,  // [H][OW]
    float* __restrict__ ws2)         // [B][H][OW][F]
{
    __shared__ float xl[WW * FF];        // 32 KB; aliased as pL after proj
    __shared__ float fsl[FF * OW];       // 32 KB  [i][swz(i,d)]
    __shared__ float fdl[FF * OW];       // 32 KB  [j][swz(j,d)]
    __shared__ float A6[OW], B4[OW];     // 1 KB
    __shared__ float redmax[16][FF];     // 4 KB
    __shared__ float redsum[16][FF];     // 4 KB
    float* pL = xl;                      // pL[i][68]: 64*68 floats < 8192

    const int b    = blockIdx.x >> 2;
    const int h    = blockIdx.x & 3;
    const int t    = threadIdx.x;
    const int wv   = t >> 6;             // 0..15 (wave id, uniform)
    const int lane = t & 63;

    // ---- stage x[b] (coalesced float4) and attention coefficients ----
    {
        const float4* xs = (const float4*)(x + (size_t)b * (WW * FF));
        ((float4*)xl)[t]        = xs[t];
        ((float4*)xl)[t + 1024] = xs[t + 1024];
        if (t < 32) {
            float4 av = *(const float4*)&attn[h * OW + t * 4];
            float4 a6, b4;
            a6.x = 0.6f * av.x; a6.y = 0.6f * av.y; a6.z = 0.6f * av.z; a6.w = 0.6f * av.w;
            b4.x = 0.4f * av.x; b4.y = 0.4f * av.y; b4.z = 0.4f * av.z; b4.w = 0.4f * av.w;
            *(float4*)&A6[t * 4] = a6;
            *(float4*)&B4[t * 4] = b4;
        }
    }
    __syncthreads();

    // ---- projection: waves 0-7 -> fs rows, 8-15 -> fd rows (16 rows each) ----
    {
        const bool is_src = wv < 8;
        const int  r0     = (wv & 7) * 16;           // d-base within head slice
        const float* Wm   = is_src ? Wsrc : Wdst;
        const float* bm   = is_src ? bsrc : bdst;
        float*       dl   = is_src ? fsl  : fdl;
        const float* wb   = Wm + (size_t)(h * OW + r0) * WW;   // wave-uniform

        float acc[16] = {};
        #pragma unroll 2
        for (int k0 = 0; k0 < WW; k0 += 4) {
            float xv[4];
            #pragma unroll
            for (int kk = 0; kk < 4; ++kk)
                xv[kk] = xl[(k0 + kk) * FF + lane];  // stride-1, 2-way = free
            #pragma unroll
            for (int rr = 0; rr < 16; ++rr) {
                float4 wr = *(const float4*)&wb[rr * WW + k0];  // uniform
                acc[rr] = fmaf(xv[0], wr.x, acc[rr]);
                acc[rr] = fmaf(xv[1], wr.y, acc[rr]);
                acc[rr] = fmaf(xv[2], wr.z, acc[rr]);
                acc[rr] = fmaf(xv[3], wr.w, acc[rr]);
            }
        }
        #pragma unroll
        for (int rr = 0; rr < 16; ++rr) {
            const int d = r0 + rr;
            dl[lane * OW + swz(lane, d)] = acc[rr] + bm[h * OW + d];
        }
    }
    __syncthreads();

    // ---- scores: thread = (j = lane, i-strip of 4 = wv*4..) ----
    float sc[4] = {0.0f, 0.0f, 0.0f, 0.0f};
    const int i0 = wv * 4;
    {
        const float* fdrow = fdl + lane * OW;
        #pragma unroll 2
        for (int c = 0; c < 32; ++c) {
            const int d0 = c * 4;
            float4 fdv = *(const float4*)&fdrow[swz(lane, d0)];  // per-lane b128
            float4 a6  = *(const float4*)&A6[d0];
            float4 b4  = *(const float4*)&B4[d0];
            #pragma unroll
            for (int ii = 0; ii < 4; ++ii) {
                const int i = i0 + ii;
                float4 fsv = *(const float4*)&fsl[i * OW + swz(i, d0)];  // bcast
                float s;
                s = fsv.x + fdv.x; sc[ii] = fmaf(a6.x, s, fmaf(b4.x, fabsf(s), sc[ii]));
                s = fsv.y + fdv.y; sc[ii] = fmaf(a6.y, s, fmaf(b4.y, fabsf(s), sc[ii]));
                s = fsv.z + fdv.z; sc[ii] = fmaf(a6.z, s, fmaf(b4.z, fabsf(s), sc[ii]));
                s = fsv.w + fdv.w; sc[ii] = fmaf(a6.w, s, fmaf(b4.w, fabsf(s), sc[ii]));
            }
        }
    }
    redmax[wv][lane] = fmaxf(fmaxf(sc[0], sc[1]), fmaxf(sc[2], sc[3]));
    __syncthreads();

    // ---- softmax over i per column j (strip-reduced, no shuffles) ----
    {
        float mj = -1e30f;
        #pragma unroll
        for (int s = 0; s < 16; ++s) mj = fmaxf(mj, redmax[s][lane]);
        float ps = 0.0f;
        #pragma unroll
        for (int ii = 0; ii < 4; ++ii) {
            float e = __expf(sc[ii] - mj);
            pL[(i0 + ii) * 68 + lane] = e;
            ps += e;
        }
        redsum[wv][lane] = ps;
    }
    __syncthreads();

    // ---- aggregation: thread = (j = lane, d-strip of 8 = wv*8..) ----
    {
        const int j  = lane;
        const int d0 = wv * 8;
        float ag[8] = {};
        #pragma unroll 2
        for (int ic = 0; ic < FF; ic += 4) {
            float p[4];
            #pragma unroll
            for (int ii = 0; ii < 4; ++ii)
                p[ii] = pL[(ic + ii) * 68 + j];          // per-lane, conflict-free
            #pragma unroll
            for (int ii = 0; ii < 4; ++ii) {
                const int i = ic + ii;
                float4 f0 = *(const float4*)&fsl[i * OW + swz(i, d0)];      // bcast
                float4 f1 = *(const float4*)&fsl[i * OW + swz(i, d0 + 4)];  // bcast
                ag[0] = fmaf(p[ii], f0.x, ag[0]);
                ag[1] = fmaf(p[ii], f0.y, ag[1]);
                ag[2] = fmaf(p[ii], f0.z, ag[2]);
                ag[3] = fmaf(p[ii], f0.w, ag[3]);
                ag[4] = fmaf(p[ii], f1.x, ag[4]);
                ag[5] = fmaf(p[ii], f1.y, ag[5]);
                ag[6] = fmaf(p[ii], f1.z, ag[6]);
                ag[7] = fmaf(p[ii], f1.w, ag[7]);
            }
        }
        float l = 0.0f;
        #pragma unroll
        for (int s = 0; s < 16; ++s) l += redsum[s][j];
        const float inv = 0.25f / l;
        float* o = ws2 + (((size_t)b * HH + h) * OW + d0) * FF + j;
        #pragma unroll
        for (int dd = 0; dd < 8; ++dd)
            o[(size_t)dd * FF] = ag[dd] * inv;           // coalesced over j
    }
}

// ---------------------------------------------------------------------------
// Head-sum (0.25 folded upstream) -> out[b][d][j].
// ---------------------------------------------------------------------------
__global__ __launch_bounds__(256) void gat_reduce(
    const float* __restrict__ ws2,   // [B][H][OW][F]
    float* __restrict__ out)         // [B][OW][F]
{
    const int g   = blockIdx.x * 256 + threadIdx.x;   // float4 index
    const int b   = g >> 11;                          // 2048 float4 per batch
    const int rem = (g & 2047) * 4;
    const float* base = ws2 + (size_t)b * (HH * OW * FF) + rem;
    float4 s0 = *(const float4*)(base);
    float4 s1 = *(const float4*)(base + OW * FF);
    float4 s2 = *(const float4*)(base + 2 * OW * FF);
    float4 s3 = *(const float4*)(base + 3 * OW * FF);
    float4 o;
    o.x = s0.x + s1.x + s2.x + s3.x;
    o.y = s0.y + s1.y + s2.y + s3.y;
    o.z = s0.z + s1.z + s2.z + s3.z;
    o.w = s0.w + s1.w + s2.w + s3.w;
    *(float4*)&out[(size_t)b * (OW * FF) + rem] = o;
}

// ---------------------------------------------------------------------------
extern "C" void kernel_launch(void* const* d_in, const int* in_sizes, int n_in,
                              void* d_out, int out_size, void* d_ws, size_t ws_size,
                              hipStream_t stream) {
    const float* x    = (const float*)d_in[0];
    const float* Wsrc = (const float*)d_in[1];
    const float* bsrc = (const float*)d_in[2];
    const float* Wdst = (const float*)d_in[3];
    const float* bdst = (const float*)d_in[4];
    const float* attn = (const float*)d_in[5];
    float* out = (float*)d_out;

    float* ws2 = (float*)d_ws;                        // [B][H][OW][F] 8 MB

    gat_fused <<<BB * HH, 1024, 0, stream>>>(x, Wsrc, bsrc, Wdst, bdst, attn, ws2);
    gat_reduce<<<512,     256,  0, stream>>>(ws2, out);
}